// Round 4
// baseline (194.242 us; speedup 1.0000x reference)
//
#include <hip/hip_runtime.h>
#include <math.h>

#define NN 20000
#define RR 32
#define HH 64
#define CC 8
#define EE 640000
#define NSTRIP 4

// ---------------------------------------------------------------- CSR build
__global__ __launch_bounds__(256) void k_zero(int* __restrict__ cnt) {
    int i = blockIdx.x * 256 + threadIdx.x;
    if (i < NN) cnt[i] = 0;
}

// 4 edges per thread, int4 loads (EE % 4 == 0)
__global__ __launch_bounds__(256) void k_hist(const int* __restrict__ ei,
                                              int* __restrict__ cnt) {
    int e = (blockIdx.x * 256 + threadIdx.x) * 4;
    if (e >= EE) return;
    int4 d = *(const int4*)(ei + EE + e);
    atomicAdd(&cnt[d.x], 1);
    atomicAdd(&cnt[d.y], 1);
    atomicAdd(&cnt[d.z], 1);
    atomicAdd(&cnt[d.w], 1);
}

// single-block scan: 1024 threads x 20 elements each (20480 >= NN)
#define SCAN_PER 20
__global__ __launch_bounds__(1024) void k_scan(const int* __restrict__ cnt,
                                               int* __restrict__ off,
                                               int* __restrict__ cur) {
    int tid = threadIdx.x;
    int base = tid * SCAN_PER;
    int v[SCAN_PER];
    int sum = 0;
    #pragma unroll
    for (int u = 0; u < SCAN_PER; u++) {
        int idx = base + u;
        v[u] = (idx < NN) ? cnt[idx] : 0;
        sum += v[u];
    }
    int lane = tid & 63, wv = tid >> 6;
    int s = sum;
    #pragma unroll
    for (int st = 1; st < 64; st <<= 1) {
        int t = __shfl_up(s, st, 64);
        if (lane >= st) s += t;
    }
    __shared__ int wsum[16];
    if (lane == 63) wsum[wv] = s;
    __syncthreads();
    if (wv == 0 && lane < 16) {
        int ws = wsum[lane];
        #pragma unroll
        for (int st = 1; st < 16; st <<= 1) {
            int t = __shfl_up(ws, st, 16);
            if (lane >= st) ws += t;
        }
        wsum[lane] = ws;
    }
    __syncthreads();
    int wbase = (wv > 0) ? wsum[wv - 1] : 0;
    int run = wbase + s - sum;
    #pragma unroll
    for (int u = 0; u < SCAN_PER; u++) {
        int idx = base + u;
        if (idx < NN) {
            cur[idx] = run;
            run += v[u];
            off[idx + 1] = run;
        }
    }
    if (tid == 0) off[0] = 0;
}

// 4 edges per thread, int4 loads
__global__ __launch_bounds__(256) void k_scatter(const int* __restrict__ ei,
                                                 const int* __restrict__ et,
                                                 int* __restrict__ cur,
                                                 unsigned* __restrict__ pk) {
    int e = (blockIdx.x * 256 + threadIdx.x) * 4;
    if (e >= EE) return;
    int4 sv = *(const int4*)(ei + e);
    int4 dv = *(const int4*)(ei + EE + e);
    int4 rv = *(const int4*)(et + e);
    pk[atomicAdd(&cur[dv.x], 1)] = (unsigned)sv.x | ((unsigned)rv.x << 15);
    pk[atomicAdd(&cur[dv.y], 1)] = (unsigned)sv.y | ((unsigned)rv.y << 15);
    pk[atomicAdd(&cur[dv.z], 1)] = (unsigned)sv.z | ((unsigned)rv.z << 15);
    pk[atomicAdd(&cur[dv.w], 1)] = (unsigned)sv.w | ((unsigned)rv.w << 15);
}

// ---------------------------------------------------------------- layer 1
// wave per dst node; lane owns h element; 8-deep load ILP
__global__ __launch_bounds__(256) void k_gather1(const unsigned* __restrict__ pk,
                                                 const int* __restrict__ off,
                                                 const float* __restrict__ W1,
                                                 const float* __restrict__ root1,
                                                 const float* __restrict__ bias1,
                                                 float* __restrict__ h) {
    int wid = (blockIdx.x * 256 + threadIdx.x) >> 6;
    int lane = threadIdx.x & 63;
    if (wid >= NN) return;
    float acc = root1[(size_t)wid * HH + lane] + bias1[lane];
    int i = off[wid], end = off[wid + 1];
    for (; i + 8 <= end; i += 8) {
        float w[8];
        #pragma unroll
        for (int u = 0; u < 8; u++) {
            unsigned p = pk[i + u];
            w[u] = W1[((size_t)(p >> 15) * NN + (p & 0x7fffu)) * HH + lane];
        }
        acc += ((w[0] + w[1]) + (w[2] + w[3])) + ((w[4] + w[5]) + (w[6] + w[7]));
    }
    for (; i < end; ++i) {
        unsigned p = pk[i];
        acc += W1[((size_t)(p >> 15) * NN + (p & 0x7fffu)) * HH + lane];
    }
    h[(size_t)wid * HH + lane] = fmaxf(acc, 0.0f);
}

// ---------------------------------------------------------------- layer 2
// thread per (r, 4-node strip): hrel[r][n][c] = sum_k h[n][k] * W2[r][k][c]
// W2[r] staged in LDS as float4 (ds_read_b128); 32 register accumulators.
__global__ __launch_bounds__(256) void k_hrel(const float* __restrict__ h,
                                              const float* __restrict__ W2,
                                              float* __restrict__ hrel) {
    __shared__ float4 w2s[HH * CC / 4];  // 128 float4 = 2 KB
    int r = blockIdx.y;
    int tid = threadIdx.x;
    if (tid < HH * CC / 4)
        w2s[tid] = ((const float4*)(W2 + (size_t)r * HH * CC))[tid];
    __syncthreads();
    int n0 = (blockIdx.x * 256 + tid) * NSTRIP;
    if (n0 >= NN) return;
    float acc[NSTRIP][CC] = {};
    for (int k = 0; k < HH; k += 4) {
        float4 w0a = w2s[(k + 0) * 2], w0b = w2s[(k + 0) * 2 + 1];
        float4 w1a = w2s[(k + 1) * 2], w1b = w2s[(k + 1) * 2 + 1];
        float4 w2a = w2s[(k + 2) * 2], w2b = w2s[(k + 2) * 2 + 1];
        float4 w3a = w2s[(k + 3) * 2], w3b = w2s[(k + 3) * 2 + 1];
        #pragma unroll
        for (int j = 0; j < NSTRIP; j++) {
            float4 hv = *(const float4*)(h + (size_t)(n0 + j) * HH + k);
            acc[j][0] += hv.x * w0a.x + hv.y * w1a.x + hv.z * w2a.x + hv.w * w3a.x;
            acc[j][1] += hv.x * w0a.y + hv.y * w1a.y + hv.z * w2a.y + hv.w * w3a.y;
            acc[j][2] += hv.x * w0a.z + hv.y * w1a.z + hv.z * w2a.z + hv.w * w3a.z;
            acc[j][3] += hv.x * w0a.w + hv.y * w1a.w + hv.z * w2a.w + hv.w * w3a.w;
            acc[j][4] += hv.x * w0b.x + hv.y * w1b.x + hv.z * w2b.x + hv.w * w3b.x;
            acc[j][5] += hv.x * w0b.y + hv.y * w1b.y + hv.z * w2b.y + hv.w * w3b.y;
            acc[j][6] += hv.x * w0b.z + hv.y * w1b.z + hv.z * w2b.z + hv.w * w3b.z;
            acc[j][7] += hv.x * w0b.w + hv.y * w1b.w + hv.z * w2b.w + hv.w * w3b.w;
        }
    }
    #pragma unroll
    for (int j = 0; j < NSTRIP; j++) {
        float* op = hrel + ((size_t)r * NN + (n0 + j)) * CC;
        *(float4*)(op)     = make_float4(acc[j][0], acc[j][1], acc[j][2], acc[j][3]);
        *(float4*)(op + 4) = make_float4(acc[j][4], acc[j][5], acc[j][6], acc[j][7]);
    }
}

// wave per dst node; gather hrel rows; fused root2 + bias2 + log-softmax
__global__ __launch_bounds__(256) void k_gather2(const unsigned* __restrict__ pk,
                                                 const int* __restrict__ off,
                                                 const float* __restrict__ h,
                                                 const float* __restrict__ hrel,
                                                 const float* __restrict__ root2,
                                                 const float* __restrict__ bias2,
                                                 float* __restrict__ out) {
    int wid = (blockIdx.x * 256 + threadIdx.x) >> 6;
    int lane = threadIdx.x & 63;
    if (wid >= NN) return;
    int kg = lane >> 3, c = lane & 7;
    float hn = h[(size_t)wid * HH + lane];
    float acc = 0.f;
    #pragma unroll
    for (int t = 0; t < 8; t++)
        acc += __shfl(hn, t, 8) * root2[(kg * 8 + t) * CC + c];
    int end = off[wid + 1];
    int i = off[wid] + kg;
    for (; i + 8 < end; i += 16) {
        unsigned p0 = pk[i], p1 = pk[i + 8];
        float v0 = hrel[((size_t)(p0 >> 15) * NN + (p0 & 0x7fffu)) * CC + c];
        float v1 = hrel[((size_t)(p1 >> 15) * NN + (p1 & 0x7fffu)) * CC + c];
        acc += v0 + v1;
    }
    for (; i < end; i += 8) {
        unsigned p = pk[i];
        acc += hrel[((size_t)(p >> 15) * NN + (p & 0x7fffu)) * CC + c];
    }
    acc += __shfl_xor(acc, 8);
    acc += __shfl_xor(acc, 16);
    acc += __shfl_xor(acc, 32);
    float x = acc + bias2[c];
    float m = x;
    m = fmaxf(m, __shfl_xor(m, 1));
    m = fmaxf(m, __shfl_xor(m, 2));
    m = fmaxf(m, __shfl_xor(m, 4));
    float ex = expf(x - m);
    ex += __shfl_xor(ex, 1);
    ex += __shfl_xor(ex, 2);
    ex += __shfl_xor(ex, 4);
    float l = m + logf(ex);
    if (lane < 8) out[(size_t)wid * CC + lane] = x - l;
}

extern "C" void kernel_launch(void* const* d_in, const int* in_sizes, int n_in,
                              void* d_out, int out_size, void* d_ws, size_t ws_size,
                              hipStream_t stream) {
    const int*   ei    = (const int*)d_in[0];    // [2, E]
    const int*   et    = (const int*)d_in[1];    // [E]
    const float* W1    = (const float*)d_in[3];  // [R, N, H]
    const float* root1 = (const float*)d_in[4];  // [N, H]
    const float* bias1 = (const float*)d_in[5];  // [H]
    const float* W2    = (const float*)d_in[6];  // [R, H, C]
    const float* root2 = (const float*)d_in[7];  // [H, C]
    const float* bias2 = (const float*)d_in[8];  // [C]
    float* out = (float*)d_out;

    char* base = (char*)d_ws;
    int*      cnt  = (int*)(base);                         // NN ints
    int*      cur  = (int*)(base + 80000);                 // NN ints
    int*      off  = (int*)(base + 160000);                // NN+1 ints
    unsigned* pk   = (unsigned*)(base + 240128);           // EE words
    float*    h    = (float*)(base + 2800128);             // NN*HH floats
    float*    hrel = (float*)(base + 7920128);             // RR*NN*CC floats
    // total ws use: 28,400,128 bytes

    k_zero   <<<(NN + 255) / 256, 256, 0, stream>>>(cnt);
    k_hist   <<<(EE / 4 + 255) / 256, 256, 0, stream>>>(ei, cnt);
    k_scan   <<<1, 1024, 0, stream>>>(cnt, off, cur);
    k_scatter<<<(EE / 4 + 255) / 256, 256, 0, stream>>>(ei, et, cur, pk);
    k_gather1<<<(NN * 64 + 255) / 256, 256, 0, stream>>>(pk, off, W1, root1, bias1, h);
    k_hrel   <<<dim3((NN / NSTRIP + 255) / 256, RR), 256, 0, stream>>>(h, W2, hrel);
    k_gather2<<<(NN * 64 + 255) / 256, 256, 0, stream>>>(pk, off, h, hrel, root2, bias2, out);
}